// Round 5
// baseline (1719.739 us; speedup 1.0000x reference)
//
#include <hip/hip_runtime.h>
#include <hip/hip_fp16.h>

// ContinuousGRULayer: B=512,T=512,D=32,H=64,L=2.
// Round-5: f16-packed weights (fma_mix) + waves_per_eu(4,4) + DPP reductions.
//   Evidence r2-r4: allocator hard-targets ~8 waves/EU and remats/spills ~100
//   fp32 weight values -> issue-bound on reload code (VGPR stuck at 64-124).
//   Fix: (1) weights stored f16x2 in d_ws (pre-pass kernel) -> 44 dwords of
//   weight regs; math stays fp32 via v_fma_mix_f32 (fma(fpext(h16),f32,f32));
//   (2) amdgpu_waves_per_eu(4,4) pins the allocator budget at 128 VGPR so the
//   ~105-reg demand is actually kept resident; (3) xor1/xor2 shuffle reduces
//   via DPP quad_perm (VALU) instead of ds_swizzle (LDS pipe).
//   Structure: grid 256 x block 512 (2 batch elems), j=tid>>3, q=tid&7.

#define NT 512
#define ND 32
#define NH 64
#define NL 2

__device__ __forceinline__ float sigm(float v) {
    return __builtin_amdgcn_rcpf(1.0f + __expf(-v));
}
__device__ __forceinline__ float tanh_(float v) {
    return 1.0f - 2.0f * __builtin_amdgcn_rcpf(1.0f + __expf(2.0f * v));
}
// xor1 / xor2 lane-pair adds on the VALU via DPP quad_perm (no LDS pipe).
__device__ __forceinline__ float dpp_add_xor1(float x) {
    int y = __builtin_amdgcn_update_dpp(0, __float_as_int(x), 0xB1, 0xF, 0xF, true);
    return x + __int_as_float(y);
}
__device__ __forceinline__ float dpp_add_xor2(float x) {
    int y = __builtin_amdgcn_update_dpp(0, __float_as_int(x), 0x4E, 0xF, 0xF, true);
    return x + __int_as_float(y);
}

// ---------- pre-pass: convert weights to f16, flow W stripped of col 64 ----------
// ws layout (halfs): Whr[L][64][64] @0, Whz @8192, Whh @16384,
//                    gWih[192][32] @24576, gWhh[192][64] @30720. total 43008.
__global__ __launch_bounds__(256) void cvt_weights(
    const float* __restrict__ Whr, const float* __restrict__ Whz,
    const float* __restrict__ Whh, const float* __restrict__ gWih,
    const float* __restrict__ gWhh, __half* __restrict__ dst)
{
    const int i = blockIdx.x * 256 + threadIdx.x;
    if (i < 24576) {
        const int a = i >> 13, rem = i & 8191;
        const int row = rem >> 6, c = rem & 63;          // row = l*64+j
        const float* src = (a == 0) ? Whr : ((a == 1) ? Whz : Whh);
        dst[i] = __float2half(src[row * 65 + c]);
    } else if (i < 30720) {
        dst[i] = __float2half(gWih[i - 24576]);
    } else if (i < 43008) {
        dst[i] = __float2half(gWhh[i - 30720]);
    }
}

__global__ __launch_bounds__(512) __attribute__((amdgpu_waves_per_eu(4, 4)))
void cgru_fused(
    const float* __restrict__ x, const float* __restrict__ tin,
    const float* __restrict__ Whr, const float* __restrict__ bhr,
    const float* __restrict__ Whz, const float* __restrict__ bhz,
    const float* __restrict__ Whh, const float* __restrict__ bhh,
    const float* __restrict__ tw,
    const float* __restrict__ gbih, const float* __restrict__ gbhh,
    const __half2* __restrict__ hw,     // packed f16 weights in d_ws
    float* __restrict__ out)
{
    const int tid = threadIdx.x;
    const int j   = tid >> 3;      // output row
    const int q   = tid & 7;       // role/k-chunk
    const int qh  = q & 3;
    const bool isZ = q >= 4;
    const int b0  = blockIdx.x * 2;

    __shared__ float hS[2][NH];
    __shared__ float rhS[2][NH];
    __shared__ float hxS[2][128];  // [h(64) | x(32) | zeros(32)]

    // packed-weight base pointers (pair indices)
    const __half2* hWr = hw;              // [L*64][32]
    const __half2* hWz = hw + 4096;
    const __half2* hWh = hw + 8192;
    const __half2* hWi = hw + 12288;      // [192][16]
    const __half2* hWg = hw + 15360;      // [192][32]

    // ---------------- one-time weight preload (f16x2) ----------------
    const __half2* Wsrc2 = isZ ? hWz : hWr;
    const float*   Wsrcf = isZ ? Whz : Whr;       // for the tt column (fp32)
    const float*   bsrc  = isZ ? bhz : bhr;
    __half2 wrz2[NL][8], wu2[NL][4];
    float w65rz[NL], w65u[NL], brz[NL], bu[NL], tws[NL];
#pragma unroll
    for (int l = 0; l < NL; ++l) {
        const int rowp = (l * NH + j) * 32;       // pair-row in flow arrays
#pragma unroll
        for (int k = 0; k < 8; ++k) wrz2[l][k] = Wsrc2[rowp + qh * 8 + k];
#pragma unroll
        for (int k = 0; k < 4; ++k) wu2[l][k]  = hWh[rowp + q * 4 + k];
        const int rowf = (l * NH + j) * (NH + 1);
        w65rz[l] = Wsrcf[rowf + NH];
        w65u[l]  = Whh[rowf + NH];
        brz[l]   = bsrc[l * NH + j];
        bu[l]    = bhh[l * NH + j];
        tws[l]   = tw[l * NH + j];
    }

    // GRU G1 row (r: j / z: 64+j): concat [gWhh_row(32 pairs) | gWih_row(16 pairs)]
    const int grow = (isZ ? NH : 0) + j;
    __half2 g12[12];
#pragma unroll
    for (int k = 0; k < 12; ++k) {
        const int m2 = qh * 12 + k;
        g12[k] = (m2 < 32) ? hWg[grow * 32 + m2] : hWi[grow * 16 + (m2 - 32)];
    }
    const float bg1 = gbih[grow] + gbhh[grow];

    // GRU G2 (n-row 128+j): q<4 -> h_n 8-pair quarters; q>=4 -> i_n 4 pairs + 4 zero
    __half2 g22[8];
    if (!isZ) {
#pragma unroll
        for (int k = 0; k < 8; ++k) g22[k] = hWg[(2 * NH + j) * 32 + qh * 8 + k];
    } else {
#pragma unroll
        for (int k = 0; k < 4; ++k) g22[k] = hWi[(2 * NH + j) * 16 + qh * 4 + k];
#pragma unroll
        for (int k = 4; k < 8; ++k) g22[k] = __floats2half2_rn(0.0f, 0.0f);
    }
    const float bin = gbih[2 * NH + j];
    const float bhn = gbhh[2 * NH + j];

    if (tid < 2 * NH) ((float*)hS)[tid] = 0.0f;
    if (tid < 2 * ND) hxS[tid >> 5][96 + (tid & 31)] = 0.0f;
    __syncthreads();

    const float* xptr = x + (size_t)(b0 + (tid >= ND ? 1 : 0)) * NT * ND;
    const float* tp0  = tin + (size_t)b0 * NT;
    const float* tp1  = tin + (size_t)(b0 + 1) * NT;
    float* op0 = out + (size_t)b0 * NT * NH;
    float* op1 = out + (size_t)(b0 + 1) * NT * NH;

    float xv = 0.0f;                       // x/t pipelined one ts ahead
    if (tid < 2 * ND) xv = xptr[tid & 31];
    float tt0 = tp0[0], tt1 = tp1[0];

    for (int ts = 0; ts < NT; ++ts) {
        float xnext = 0.0f, ttn0 = 0.0f, ttn1 = 0.0f;
        if (ts + 1 < NT) {
            if (tid < 2 * ND) xnext = xptr[(ts + 1) * ND + (tid & 31)];
            ttn0 = tp0[ts + 1];
            ttn1 = tp1[ts + 1];
        }

        // =================== GRU-flow layers ===================
#pragma unroll
        for (int l = 0; l < NL; ++l) {
            // ---- r/z pass: 16-wide k-quarter (8 f16 pairs) ----
            float a0 = 0.0f, a1 = 0.0f;
            {
                const float* hp0 = &hS[0][qh * 16];
                const float* hp1 = &hS[1][qh * 16];
#pragma unroll
                for (int k = 0; k < 8; ++k) {
                    const float wl = __low2float(wrz2[l][k]);
                    const float wh = __high2float(wrz2[l][k]);
                    a0 = fmaf(wl, hp0[2 * k], a0); a0 = fmaf(wh, hp0[2 * k + 1], a0);
                    a1 = fmaf(wl, hp1[2 * k], a1); a1 = fmaf(wh, hp1[2 * k + 1], a1);
                }
            }
            a0 = dpp_add_xor1(a0); a0 = dpp_add_xor2(a0);
            a1 = dpp_add_xor1(a1); a1 = dpp_add_xor2(a1);
            const float s0 = sigm(a0 + w65rz[l] * tt0 + brz[l]);
            const float s1 = sigm(a1 + w65rz[l] * tt1 + brz[l]);
            const float zv0 = 0.4f * s0, zv1 = 0.4f * s1;
            if (q == 0) {
                rhS[0][j] = (0.8f * s0) * hS[0][j];
                rhS[1][j] = (0.8f * s1) * hS[1][j];
            }
            __syncthreads();

            // ---- u pass: 8-wide k-eighth (4 pairs) ----
            float u0 = 0.0f, u1 = 0.0f;
            {
                const float* rp0 = &rhS[0][q * 8];
                const float* rp1 = &rhS[1][q * 8];
#pragma unroll
                for (int k = 0; k < 4; ++k) {
                    const float wl = __low2float(wu2[l][k]);
                    const float wh = __high2float(wu2[l][k]);
                    u0 = fmaf(wl, rp0[2 * k], u0); u0 = fmaf(wh, rp0[2 * k + 1], u0);
                    u1 = fmaf(wl, rp1[2 * k], u1); u1 = fmaf(wh, rp1[2 * k + 1], u1);
                }
            }
            u0 = dpp_add_xor1(u0); u0 = dpp_add_xor2(u0); u0 += __shfl_xor(u0, 4);
            u1 = dpp_add_xor1(u1); u1 = dpp_add_xor2(u1); u1 += __shfl_xor(u1, 4);
            if (l == NL - 1 && tid < 2 * ND)
                hxS[tid >> 5][NH + (tid & 31)] = xv;
            const float uu0 = tanh_(u0 + w65u[l] * tt0 + bu[l]);
            const float uu1 = tanh_(u1 + w65u[l] * tt1 + bu[l]);
            if (q == 4) {
                const float h0 = hS[0][j];
                const float h1 = hS[1][j];
                const float hn0 = fmaf(tanh_(tws[l] * tt0) * zv0, uu0 - h0, h0);
                const float hn1 = fmaf(tanh_(tws[l] * tt1) * zv1, uu1 - h1, h1);
                hS[0][j] = hn0;
                hS[1][j] = hn1;
                if (l == NL - 1) {
                    hxS[0][j] = hn0;
                    hxS[1][j] = hn1;
                    op0[ts * NH + j] = hn0;
                    op1[ts * NH + j] = hn1;
                }
            }
            __syncthreads();
        }

        // =================== GRU cell ===================
        float p0 = 0.0f, p1 = 0.0f;
        {
            const float* gp0 = &hxS[0][qh * 24];
            const float* gp1 = &hxS[1][qh * 24];
#pragma unroll
            for (int k = 0; k < 12; ++k) {
                const float wl = __low2float(g12[k]);
                const float wh = __high2float(g12[k]);
                p0 = fmaf(wl, gp0[2 * k], p0); p0 = fmaf(wh, gp0[2 * k + 1], p0);
                p1 = fmaf(wl, gp1[2 * k], p1); p1 = fmaf(wh, gp1[2 * k + 1], p1);
            }
        }
        p0 = dpp_add_xor1(p0); p0 = dpp_add_xor2(p0);
        p1 = dpp_add_xor1(p1); p1 = dpp_add_xor2(p1);
        const float gate0 = sigm(p0 + bg1);
        const float gate1 = sigm(p1 + bg1);
        const float oth0  = __shfl_xor(gate0, 4);
        const float oth1  = __shfl_xor(gate1, 4);
        const float r0 = isZ ? oth0 : gate0;
        const float r1 = isZ ? oth1 : gate1;
        const float z0 = isZ ? gate0 : oth0;
        const float z1 = isZ ? gate1 : oth1;

        float d0 = 0.0f, d1 = 0.0f;
        {
            const int off = isZ ? (NH + qh * 8) : (qh * 16);
            const float* dp0 = &hxS[0][off];
            const float* dp1 = &hxS[1][off];
#pragma unroll
            for (int k = 0; k < 8; ++k) {
                const float wl = __low2float(g22[k]);
                const float wh = __high2float(g22[k]);
                d0 = fmaf(wl, dp0[2 * k], d0); d0 = fmaf(wh, dp0[2 * k + 1], d0);
                d1 = fmaf(wl, dp1[2 * k], d1); d1 = fmaf(wh, dp1[2 * k + 1], d1);
            }
        }
        d0 = dpp_add_xor1(d0); d0 = dpp_add_xor2(d0);
        d1 = dpp_add_xor1(d1); d1 = dpp_add_xor2(d1);
        const float e0 = __shfl_xor(d0, 4);
        const float e1 = __shfl_xor(d1, 4);
        const float hnd0 = isZ ? e0 : d0;
        const float hnd1 = isZ ? e1 : d1;
        const float ind0 = isZ ? d0 : e0;
        const float ind1 = isZ ? d1 : e1;

        const float n0 = tanh_(ind0 + bin + r0 * (hnd0 + bhn));
        const float n1 = tanh_(ind1 + bin + r1 * (hnd1 + bhn));
        const float hj0 = hxS[0][j];
        const float hj1 = hxS[1][j];
        const float hp20 = (1.0f - z0) * n0 + z0 * hj0;
        const float hp21 = (1.0f - z1) * n1 + z1 * hj1;
        if (q == 0) {
            hS[0][j] = hp20;
            hS[1][j] = hp21;
        }
        __syncthreads();

        xv = xnext; tt0 = ttn0; tt1 = ttn1;
    }
}

extern "C" void kernel_launch(void* const* d_in, const int* in_sizes, int n_in,
                              void* d_out, int out_size, void* d_ws, size_t ws_size,
                              hipStream_t stream) {
    const float* x    = (const float*)d_in[0];
    const float* tin  = (const float*)d_in[1];
    const float* Whr  = (const float*)d_in[2];
    const float* bhr  = (const float*)d_in[3];
    const float* Whz  = (const float*)d_in[4];
    const float* bhz  = (const float*)d_in[5];
    const float* Whh  = (const float*)d_in[6];
    const float* bhh  = (const float*)d_in[7];
    const float* tw   = (const float*)d_in[8];
    const float* gWih = (const float*)d_in[9];
    const float* gWhh = (const float*)d_in[10];
    const float* gbih = (const float*)d_in[11];
    const float* gbhh = (const float*)d_in[12];
    float* out = (float*)d_out;
    __half* hws = (__half*)d_ws;

    hipLaunchKernelGGL(cvt_weights, dim3(168), dim3(256), 0, stream,
                       Whr, Whz, Whh, gWih, gWhh, hws);
    hipLaunchKernelGGL(cgru_fused, dim3(256), dim3(512), 0, stream,
                       x, tin, Whr, bhr, Whz, bhz, Whh, bhh, tw,
                       gbih, gbhh, (const __half2*)hws, out);
}